// Round 8
// baseline (2785.432 us; speedup 1.0000x reference)
//
#include <hip/hip_runtime.h>
#include <hip/hip_bf16.h>

typedef __hip_bfloat16 bf16_t;
typedef __bf16 bf16x8 __attribute__((ext_vector_type(8)));      // 16x16x32 A/B frag
typedef __bf16 bf16x4 __attribute__((ext_vector_type(4)));      // 16x16x16 A/B frag
typedef short  s16x4  __attribute__((ext_vector_type(4)));
typedef float  f32x4  __attribute__((ext_vector_type(4)));      // C/D frag

#define MFMA(a, b, c) __builtin_amdgcn_mfma_f32_16x16x32_bf16((a), (b), (c), 0, 0, 0)

__device__ __forceinline__ f32x4 mfma16(bf16x4 a, bf16x4 b, f32x4 c) {
#if __has_builtin(__builtin_amdgcn_mfma_f32_16x16x16_bf16)
  return __builtin_amdgcn_mfma_f32_16x16x16_bf16(a, b, c, 0, 0, 0);
#else
  return __builtin_amdgcn_mfma_f32_16x16x16bf16_1k(
      __builtin_bit_cast(s16x4, a), __builtin_bit_cast(s16x4, b), c, 0, 0, 0);
#endif
}

__device__ __forceinline__ bf16x8 ldg8(const bf16_t* p) {
  return *reinterpret_cast<const bf16x8*>(p);
}
__device__ __forceinline__ bf16x4 ldg4(const bf16_t* p) {
  return *reinterpret_cast<const bf16x4*>(p);
}
__device__ __forceinline__ void st8(bf16_t* p, bf16x8 v) {
  *reinterpret_cast<bf16x8*>(p) = v;
}
__device__ __forceinline__ void store_out(bf16_t* p, float v) { *p = __float2bfloat16(v); }
__device__ __forceinline__ void store_out(float* p, float v)  { *p = v; }

// async global->LDS, 16B per lane. LDS dest is wave-uniform base + lane*16.
__device__ __forceinline__ void async16(const bf16_t* g, bf16_t* l) {
  __builtin_amdgcn_global_load_lds(
      (const __attribute__((address_space(1))) void*)g,
      (__attribute__((address_space(3))) void*)l, 16, 0, 0);
}

// ---------------------------------------------------------------------------
// f32 -> bf16 conversion; folds softmax scale (1/8 * log2e) into Wq.
// ---------------------------------------------------------------------------
__global__ __launch_bounds__(256) void cvt_kernel(
    const float* __restrict__ x,  const float* __restrict__ Wq,
    const float* __restrict__ Wk, const float* __restrict__ Wv,
    const float* __restrict__ Wo,
    bf16_t* __restrict__ xb,  bf16_t* __restrict__ Wqb,
    bf16_t* __restrict__ Wkb, bf16_t* __restrict__ Wvb,
    bf16_t* __restrict__ Wob) {
  const int bid = blockIdx.x;
  const float* src; bf16_t* dst; size_t base;
  float scl = 1.0f;
  if (bid < 2048)      { src = x;  dst = xb;  base = (size_t)bid * 2048; }
  else if (bid < 2560) { src = Wq; dst = Wqb; base = (size_t)(bid - 2048) * 2048;
                         scl = 0.180336878f; }  // 0.125 * log2(e)
  else if (bid < 3072) { src = Wk; dst = Wkb; base = (size_t)(bid - 2560) * 2048; }
  else if (bid < 3584) { src = Wv; dst = Wvb; base = (size_t)(bid - 3072) * 2048; }
  else                 { src = Wo; dst = Wob; base = (size_t)(bid - 3584) * 2048; }
  const size_t i0 = base + (size_t)threadIdx.x * 8;
  const float4 f0 = *reinterpret_cast<const float4*>(src + i0);
  const float4 f1 = *reinterpret_cast<const float4*>(src + i0 + 4);
  bf16x8 v;
  v[0] = (__bf16)(f0.x * scl); v[1] = (__bf16)(f0.y * scl);
  v[2] = (__bf16)(f0.z * scl); v[3] = (__bf16)(f0.w * scl);
  v[4] = (__bf16)(f1.x * scl); v[5] = (__bf16)(f1.y * scl);
  v[6] = (__bf16)(f1.z * scl); v[7] = (__bf16)(f1.w * scl);
  st8(dst + i0, v);
}

// ---------------------------------------------------------------------------
// GEMM tile: C[128x128] = A[128xK] * B[128xK]^T, K=1024, BK=64.
// global_load_lds width-16 staging with XOR-chunk swizzle.  (unchanged, R6)
// ---------------------------------------------------------------------------
#define GK 1024

template <typename OutT, bool BIAS>
__device__ __forceinline__ void gemm_tile(
    const bf16_t* __restrict__ A, const bf16_t* __restrict__ B,
    OutT* __restrict__ C, const float* __restrict__ bias,
    int bm, int bn, int ldc, bf16_t* As, bf16_t* Bs) {
  const int tid  = threadIdx.x;
  const int lane = tid & 63;
  const int wave = tid >> 6;
  const int wm   = (wave & 1) << 6;
  const int wn   = (wave >> 1) << 6;
  const int lr   = lane & 15;
  const int lq   = lane >> 4;

  const int srow = tid >> 3;                        // 0..31
  const int sx   = ((tid & 7) ^ (srow & 7)) << 3;   // swizzled source offset

  const bf16_t* Ag = A + (size_t)(bm + srow) * GK + sx;
  const bf16_t* Bg = B + (size_t)(bn + srow) * GK + sx;
  bf16_t* Asw = As + wave * 512;
  bf16_t* Bsw = Bs + wave * 512;

  f32x4 acc[4][4];
#pragma unroll
  for (int i = 0; i < 4; ++i)
#pragma unroll
    for (int j = 0; j < 4; ++j) acc[i][j] = (f32x4){0.f, 0.f, 0.f, 0.f};

  for (int k0 = 0; k0 < GK; k0 += 64) {
    __syncthreads();
#pragma unroll
    for (int g = 0; g < 4; ++g) {
      async16(Ag + k0 + (size_t)(g * 32) * GK, Asw + g * 2048);
      async16(Bg + k0 + (size_t)(g * 32) * GK, Bsw + g * 2048);
    }
    __syncthreads();
#pragma unroll
    for (int ks = 0; ks < 2; ++ks) {
      bf16x8 af[4], bf[4];
      const int chs = ((ks * 4 + lq) ^ (lr & 7)) << 3;
#pragma unroll
      for (int i = 0; i < 4; ++i) {
        af[i] = ldg8(&As[(wm + i * 16 + lr) * 64 + chs]);
        bf[i] = ldg8(&Bs[(wn + i * 16 + lr) * 64 + chs]);
      }
#pragma unroll
      for (int mi = 0; mi < 4; ++mi)
#pragma unroll
        for (int ni = 0; ni < 4; ++ni)
          acc[mi][ni] = MFMA(af[mi], bf[ni], acc[mi][ni]);
    }
  }

  // C/D layout: col = lane&15, row = (lane>>4)*4 + r  (m89-verified)
#pragma unroll
  for (int ni = 0; ni < 4; ++ni) {
    const int col = bn + wn + ni * 16 + lr;
    float bv = 0.f;
    if (BIAS) bv = bias[col];
#pragma unroll
    for (int mi = 0; mi < 4; ++mi) {
#pragma unroll
      for (int r = 0; r < 4; ++r) {
        const int row = bm + wm + mi * 16 + lq * 4 + r;
        store_out(&C[(size_t)row * ldc + col], acc[mi][ni][r] + bv);
      }
    }
  }
}

// XCD-aware remap: same-x-tile blocks share bid%8 -> same XCD L2.
// z=0: Q = x Wq^T;  z=1: K = x Wk^T;  z=2: Vt = Wv x^T [1024x4096]
__global__ __launch_bounds__(256) void qkv_kernel(
    const bf16_t* __restrict__ x, const bf16_t* __restrict__ Wq,
    const bf16_t* __restrict__ Wk, const bf16_t* __restrict__ Wv,
    bf16_t* __restrict__ Q, bf16_t* __restrict__ Kp, bf16_t* __restrict__ Vt) {
  __shared__ alignas(16) bf16_t As[128 * 64];
  __shared__ alignas(16) bf16_t Bs[128 * 64];
  const int bid = blockIdx.x;
  const int z   = blockIdx.y;
  const int mt  = (bid & 31) * 128;   // x token-tile; XCD = bid%8 = mt-tile%8
  const int nt  = (bid >> 5) * 128;
  if (z == 0) {
    gemm_tile<bf16_t, false>(x, Wq, Q, nullptr, mt, nt, 1024, As, Bs);
  } else if (z == 1) {
    gemm_tile<bf16_t, false>(x, Wk, Kp, nullptr, mt, nt, 1024, As, Bs);
  } else {
    gemm_tile<bf16_t, false>(Wv, x, Vt, nullptr, nt, mt, 4096, As, Bs);
  }
}

__global__ __launch_bounds__(256) void out_proj_kernel(
    const bf16_t* __restrict__ Ao, const bf16_t* __restrict__ Wo,
    const float* __restrict__ bias, float* __restrict__ out) {
  __shared__ alignas(16) bf16_t As[128 * 64];
  __shared__ alignas(16) bf16_t Bs[128 * 64];
  const int bid = blockIdx.x;
  gemm_tile<float, true>(Ao, Wo, out, bias, (bid & 31) * 128, (bid >> 5) * 128, 1024, As, Bs);
}

// ---------------------------------------------------------------------------
// Attention R8: R6 wave structure (32 q-rows/wave, full kv per wave) +
// KV tile 128 (16 iters, half the barriers) + register double-buffered
// staging: tile t+1's 8 global b128 loads issue right after tile t's LDS
// stores and overlap the whole 8-step compute phase.
// S^T = K(A,LDS) x Q(B,regs) via 16x16x32; C-layout (kv=lq*4+r, q=lr) equals
// the 16x16x16 B-layout, so P = exp2(S^T) feeds O^T += Vt(A,LDS) x P from
// registers. l per-lane + 2 end shuffles. Epilogue transpose via LDS overlay.
// ---------------------------------------------------------------------------
#define VPAD 132   // V row stride (128 kv + 4): stride 66 words ≡ 2 mod 32 -> 2-way, free

__global__ __launch_bounds__(256) void attn_kernel(
    const bf16_t* __restrict__ Q, const bf16_t* __restrict__ Kp,
    const bf16_t* __restrict__ Vt, bf16_t* __restrict__ Ao) {
  __shared__ alignas(16) char smem_raw[16384 + 64 * VPAD * 2];  // 33280 B
  bf16_t* Ks  = (bf16_t*)smem_raw;                 // [128 kv][64 hd], swizzled chunks
  bf16_t* Vs  = (bf16_t*)(smem_raw + 16384);       // [64 hd][VPAD kv]
  float*  Osc = (float*)smem_raw;                  // epilogue overlay (17408 B used)

  const int tid  = threadIdx.x;
  const int lane = tid & 63;
  const int wave = tid >> 6;
  const int lr   = lane & 15;
  const int lq   = lane >> 4;
  const int bh   = blockIdx.x;
  const int qt   = blockIdx.y;
  const int b    = bh >> 4;
  const int h    = bh & 15;
  const size_t tok0 = (size_t)b * 2048;
  const int col0 = h * 64;
  const int qblk = qt * 128 + wave * 32;           // wave's 32 q-rows

  // Q B-frags (n = q = lane&15, k = hd = c*32 + lq*8 + i), held in regs
  bf16x8 qf[2][2];
#pragma unroll
  for (int nt = 0; nt < 2; ++nt) {
    const size_t qrow = tok0 + qblk + nt * 16 + lr;
#pragma unroll
    for (int c = 0; c < 2; ++c)
      qf[nt][c] = ldg8(&Q[qrow * 1024 + col0 + c * 32 + lq * 8]);
  }

  f32x4 o[2][4];  // O^T accum per nt: D[m=hd=ht*16+lq*4+r][n=q=lr]
#pragma unroll
  for (int nt = 0; nt < 2; ++nt)
#pragma unroll
    for (int i = 0; i < 4; ++i) o[nt][i] = (f32x4){0.f, 0.f, 0.f, 0.f};
  float lsum[2] = {0.f, 0.f};

  // staging geometry (per thread: 4 K rows, 2 V rows x 2 chunks)
  const int srow = tid >> 3;                       // 0..31
  const int sxk  = ((tid & 7) ^ (srow & 7)) << 3;  // K swizzled source chunk
  const int sc0  = (tid & 7) << 3;                 // V chunk (kv 0..63)
  const int sc1  = sc0 + 64;                       // V chunk (kv 64..127)

  // frag-read LDS offsets
  const int kch0 = (lq ^ (lr & 7)) << 3;
  const int kch1 = ((lq + 4) ^ (lr & 7)) << 3;
  const int voff = lr * VPAD + lq * 4;

  // register double-buffer for staging
  bf16x8 kr[2][4], vr[2][4];
  {
    const bf16_t* Kg = Kp + tok0 * 1024 + col0;
    const bf16_t* Vg = Vt + (size_t)col0 * 4096 + tok0;
#pragma unroll
    for (int j = 0; j < 4; ++j) kr[0][j] = ldg8(Kg + (size_t)(srow + 32 * j) * 1024 + sxk);
    vr[0][0] = ldg8(Vg + (size_t)srow * 4096 + sc0);
    vr[0][1] = ldg8(Vg + (size_t)srow * 4096 + sc1);
    vr[0][2] = ldg8(Vg + (size_t)(srow + 32) * 4096 + sc0);
    vr[0][3] = ldg8(Vg + (size_t)(srow + 32) * 4096 + sc1);
  }

  for (int t = 0; t < 16; ++t) {
    const int cur = t & 1;
    __syncthreads();   // previous tile's consumers done
#pragma unroll
    for (int j = 0; j < 4; ++j) st8(&Ks[(size_t)tid * 8 + j * 2048], kr[cur][j]);
    st8(&Vs[srow * VPAD + sc0], vr[cur][0]);
    st8(&Vs[srow * VPAD + sc1], vr[cur][1]);
    st8(&Vs[(srow + 32) * VPAD + sc0], vr[cur][2]);
    st8(&Vs[(srow + 32) * VPAD + sc1], vr[cur][3]);
    __syncthreads();

    if (t < 15) {      // prefetch next tile; overlaps compute below
      const int nxt = cur ^ 1;
      const size_t kv0 = (size_t)(t + 1) * 128;
      const bf16_t* Kg = Kp + (tok0 + kv0) * 1024 + col0;
      const bf16_t* Vg = Vt + (size_t)col0 * 4096 + tok0 + kv0;
#pragma unroll
      for (int j = 0; j < 4; ++j) kr[nxt][j] = ldg8(Kg + (size_t)(srow + 32 * j) * 1024 + sxk);
      vr[nxt][0] = ldg8(Vg + (size_t)srow * 4096 + sc0);
      vr[nxt][1] = ldg8(Vg + (size_t)srow * 4096 + sc1);
      vr[nxt][2] = ldg8(Vg + (size_t)(srow + 32) * 4096 + sc0);
      vr[nxt][3] = ldg8(Vg + (size_t)(srow + 32) * 4096 + sc1);
    }

#pragma unroll
    for (int c = 0; c < 8; ++c) {
      const bf16x8 kf0 = ldg8(&Ks[(c * 16 + lr) * 64 + kch0]);
      const bf16x8 kf1 = ldg8(&Ks[(c * 16 + lr) * 64 + kch1]);
      bf16x4 pb[2];
#pragma unroll
      for (int nt = 0; nt < 2; ++nt) {
        f32x4 sT = {0.f, 0.f, 0.f, 0.f};
        sT = MFMA(kf0, qf[nt][0], sT);
        sT = MFMA(kf1, qf[nt][1], sT);
        const float p0 = exp2f(sT.x);
        const float p1 = exp2f(sT.y);
        const float p2 = exp2f(sT.z);
        const float p3 = exp2f(sT.w);
        pb[nt][0] = (__bf16)p0; pb[nt][1] = (__bf16)p1;
        pb[nt][2] = (__bf16)p2; pb[nt][3] = (__bf16)p3;
        lsum[nt] += (p0 + p1) + (p2 + p3);
      }
#pragma unroll
      for (int ht = 0; ht < 4; ++ht) {
        const bf16x4 vf = ldg4(&Vs[(ht * 16 + lr) * VPAD + lq * 4 + c * 16]);
        o[0][ht] = mfma16(vf, pb[0], o[0][ht]);
        o[1][ht] = mfma16(vf, pb[1], o[1][ht]);
      }
    }
  }

  // all waves done with Ks/Vs before overlaying epilogue scratch
  __syncthreads();

  float* Ow = &Osc[wave * 64 * 17];
#pragma unroll
  for (int nt = 0; nt < 2; ++nt) {
    float ls = lsum[nt];
    ls += __shfl_xor(ls, 16);
    ls += __shfl_xor(ls, 32);
    const float invl = 1.f / ls;

    // wave-private transpose bounce (in-wave DS ordering, no barrier)
#pragma unroll
    for (int ht = 0; ht < 4; ++ht)
#pragma unroll
      for (int r = 0; r < 4; ++r)
        Ow[(ht * 16 + lq * 4 + r) * 17 + lr] = o[nt][ht][r] * invl;

    const int qq = lane >> 2;          // 0..15
    const int hc = (lane & 3) * 16;    // hd segment
    bf16x8 w0, w1;
#pragma unroll
    for (int i = 0; i < 8; ++i) {
      w0[i] = (__bf16)Ow[(hc + i) * 17 + qq];
      w1[i] = (__bf16)Ow[(hc + 8 + i) * 17 + qq];
    }
    bf16_t* dst = Ao + (tok0 + qblk + nt * 16 + qq) * 1024 + col0 + hc;
    st8(dst, w0);
    st8(dst + 8, w1);
  }
}

extern "C" void kernel_launch(void* const* d_in, const int* in_sizes, int n_in,
                              void* d_out, int out_size, void* d_ws, size_t ws_size,
                              hipStream_t stream) {
  const float* x  = (const float*)d_in[0];
  const float* Wq = (const float*)d_in[1];
  const float* Wk = (const float*)d_in[2];
  const float* Wv = (const float*)d_in[3];
  const float* Wo = (const float*)d_in[4];
  const float* bo = (const float*)d_in[5];
  float* out = (float*)d_out;

  const size_t NTOK = 4096, DMODEL = 1024, WSZ = DMODEL * DMODEL;
  bf16_t* xb  = (bf16_t*)d_ws;
  bf16_t* Wqb = xb + NTOK * DMODEL;
  bf16_t* Wkb = Wqb + WSZ;
  bf16_t* Wvb = Wkb + WSZ;
  bf16_t* Wob = Wvb + WSZ;
  bf16_t* Q   = Wob + WSZ;
  bf16_t* Kp  = Q  + NTOK * DMODEL;
  bf16_t* Vt  = Kp + NTOK * DMODEL;            // [1024][4096] = V^T
  bf16_t* Ao  = Vt + NTOK * DMODEL;

  cvt_kernel<<<dim3(4096), 256, 0, stream>>>(x, Wq, Wk, Wv, Wo, xb, Wqb, Wkb, Wvb, Wob);
  qkv_kernel<<<dim3(256, 3), 256, 0, stream>>>(xb, Wqb, Wkb, Wvb, Q, Kp, Vt);
  attn_kernel<<<dim3(32, 16), 256, 0, stream>>>(Q, Kp, Vt, Ao);
  out_proj_kernel<<<dim3(256, 1), 256, 0, stream>>>(Ao, Wob, bo, out);
}

// Round 9
// 222.736 us; speedup vs baseline: 12.5055x; 12.5055x over previous
//
#include <hip/hip_runtime.h>
#include <hip/hip_bf16.h>

typedef __hip_bfloat16 bf16_t;
typedef __bf16 bf16x8 __attribute__((ext_vector_type(8)));      // 16x16x32 A/B frag
typedef __bf16 bf16x4 __attribute__((ext_vector_type(4)));      // 16x16x16 A/B frag
typedef short  s16x4  __attribute__((ext_vector_type(4)));
typedef float  f32x4  __attribute__((ext_vector_type(4)));      // C/D frag

#define MFMA(a, b, c) __builtin_amdgcn_mfma_f32_16x16x32_bf16((a), (b), (c), 0, 0, 0)

__device__ __forceinline__ f32x4 mfma16(bf16x4 a, bf16x4 b, f32x4 c) {
#if __has_builtin(__builtin_amdgcn_mfma_f32_16x16x16_bf16)
  return __builtin_amdgcn_mfma_f32_16x16x16_bf16(a, b, c, 0, 0, 0);
#else
  return __builtin_amdgcn_mfma_f32_16x16x16bf16_1k(
      __builtin_bit_cast(s16x4, a), __builtin_bit_cast(s16x4, b), c, 0, 0, 0);
#endif
}

__device__ __forceinline__ bf16x8 ldg8(const bf16_t* p) {
  return *reinterpret_cast<const bf16x8*>(p);
}
__device__ __forceinline__ bf16x4 ldg4(const bf16_t* p) {
  return *reinterpret_cast<const bf16x4*>(p);
}
__device__ __forceinline__ void st8(bf16_t* p, bf16x8 v) {
  *reinterpret_cast<bf16x8*>(p) = v;
}
__device__ __forceinline__ void store_out(bf16_t* p, float v) { *p = __float2bfloat16(v); }
__device__ __forceinline__ void store_out(float* p, float v)  { *p = v; }

// async global->LDS, 16B per lane. LDS dest is wave-uniform base + lane*16.
__device__ __forceinline__ void async16(const bf16_t* g, bf16_t* l) {
  __builtin_amdgcn_global_load_lds(
      (const __attribute__((address_space(1))) void*)g,
      (__attribute__((address_space(3))) void*)l, 16, 0, 0);
}

// ---------------------------------------------------------------------------
// f32 -> bf16 conversion; folds softmax scale (1/8 * log2e) into Wq.
// ---------------------------------------------------------------------------
__global__ __launch_bounds__(256) void cvt_kernel(
    const float* __restrict__ x,  const float* __restrict__ Wq,
    const float* __restrict__ Wk, const float* __restrict__ Wv,
    const float* __restrict__ Wo,
    bf16_t* __restrict__ xb,  bf16_t* __restrict__ Wqb,
    bf16_t* __restrict__ Wkb, bf16_t* __restrict__ Wvb,
    bf16_t* __restrict__ Wob) {
  const int bid = blockIdx.x;
  const float* src; bf16_t* dst; size_t base;
  float scl = 1.0f;
  if (bid < 2048)      { src = x;  dst = xb;  base = (size_t)bid * 2048; }
  else if (bid < 2560) { src = Wq; dst = Wqb; base = (size_t)(bid - 2048) * 2048;
                         scl = 0.180336878f; }  // 0.125 * log2(e)
  else if (bid < 3072) { src = Wk; dst = Wkb; base = (size_t)(bid - 2560) * 2048; }
  else if (bid < 3584) { src = Wv; dst = Wvb; base = (size_t)(bid - 3072) * 2048; }
  else                 { src = Wo; dst = Wob; base = (size_t)(bid - 3584) * 2048; }
  const size_t i0 = base + (size_t)threadIdx.x * 8;
  const float4 f0 = *reinterpret_cast<const float4*>(src + i0);
  const float4 f1 = *reinterpret_cast<const float4*>(src + i0 + 4);
  bf16x8 v;
  v[0] = (__bf16)(f0.x * scl); v[1] = (__bf16)(f0.y * scl);
  v[2] = (__bf16)(f0.z * scl); v[3] = (__bf16)(f0.w * scl);
  v[4] = (__bf16)(f1.x * scl); v[5] = (__bf16)(f1.y * scl);
  v[6] = (__bf16)(f1.z * scl); v[7] = (__bf16)(f1.w * scl);
  st8(dst + i0, v);
}

// ---------------------------------------------------------------------------
// GEMM tile: C[128x128] = A[128xK] * B[128xK]^T, K=1024, BK=64.
// global_load_lds width-16 staging with XOR-chunk swizzle.  (unchanged, R6)
// ---------------------------------------------------------------------------
#define GK 1024

template <typename OutT, bool BIAS>
__device__ __forceinline__ void gemm_tile(
    const bf16_t* __restrict__ A, const bf16_t* __restrict__ B,
    OutT* __restrict__ C, const float* __restrict__ bias,
    int bm, int bn, int ldc, bf16_t* As, bf16_t* Bs) {
  const int tid  = threadIdx.x;
  const int lane = tid & 63;
  const int wave = tid >> 6;
  const int wm   = (wave & 1) << 6;
  const int wn   = (wave >> 1) << 6;
  const int lr   = lane & 15;
  const int lq   = lane >> 4;

  const int srow = tid >> 3;                        // 0..31
  const int sx   = ((tid & 7) ^ (srow & 7)) << 3;   // swizzled source offset

  const bf16_t* Ag = A + (size_t)(bm + srow) * GK + sx;
  const bf16_t* Bg = B + (size_t)(bn + srow) * GK + sx;
  bf16_t* Asw = As + wave * 512;
  bf16_t* Bsw = Bs + wave * 512;

  f32x4 acc[4][4];
#pragma unroll
  for (int i = 0; i < 4; ++i)
#pragma unroll
    for (int j = 0; j < 4; ++j) acc[i][j] = (f32x4){0.f, 0.f, 0.f, 0.f};

  for (int k0 = 0; k0 < GK; k0 += 64) {
    __syncthreads();
#pragma unroll
    for (int g = 0; g < 4; ++g) {
      async16(Ag + k0 + (size_t)(g * 32) * GK, Asw + g * 2048);
      async16(Bg + k0 + (size_t)(g * 32) * GK, Bsw + g * 2048);
    }
    __syncthreads();
#pragma unroll
    for (int ks = 0; ks < 2; ++ks) {
      bf16x8 af[4], bf[4];
      const int chs = ((ks * 4 + lq) ^ (lr & 7)) << 3;
#pragma unroll
      for (int i = 0; i < 4; ++i) {
        af[i] = ldg8(&As[(wm + i * 16 + lr) * 64 + chs]);
        bf[i] = ldg8(&Bs[(wn + i * 16 + lr) * 64 + chs]);
      }
#pragma unroll
      for (int mi = 0; mi < 4; ++mi)
#pragma unroll
        for (int ni = 0; ni < 4; ++ni)
          acc[mi][ni] = MFMA(af[mi], bf[ni], acc[mi][ni]);
    }
  }

  // C/D layout: col = lane&15, row = (lane>>4)*4 + r  (m89-verified)
#pragma unroll
  for (int ni = 0; ni < 4; ++ni) {
    const int col = bn + wn + ni * 16 + lr;
    float bv = 0.f;
    if (BIAS) bv = bias[col];
#pragma unroll
    for (int mi = 0; mi < 4; ++mi) {
#pragma unroll
      for (int r = 0; r < 4; ++r) {
        const int row = bm + wm + mi * 16 + lq * 4 + r;
        store_out(&C[(size_t)row * ldc + col], acc[mi][ni][r] + bv);
      }
    }
  }
}

// XCD-aware remap: same-x-tile blocks share bid%8 -> same XCD L2.
// z=0: Q = x Wq^T;  z=1: K = x Wk^T;  z=2: Vt = Wv x^T [1024x4096]
__global__ __launch_bounds__(256) void qkv_kernel(
    const bf16_t* __restrict__ x, const bf16_t* __restrict__ Wq,
    const bf16_t* __restrict__ Wk, const bf16_t* __restrict__ Wv,
    bf16_t* __restrict__ Q, bf16_t* __restrict__ Kp, bf16_t* __restrict__ Vt) {
  __shared__ alignas(16) bf16_t As[128 * 64];
  __shared__ alignas(16) bf16_t Bs[128 * 64];
  const int bid = blockIdx.x;
  const int z   = blockIdx.y;
  const int mt  = (bid & 31) * 128;   // x token-tile; XCD = bid%8 = mt-tile%8
  const int nt  = (bid >> 5) * 128;
  if (z == 0) {
    gemm_tile<bf16_t, false>(x, Wq, Q, nullptr, mt, nt, 1024, As, Bs);
  } else if (z == 1) {
    gemm_tile<bf16_t, false>(x, Wk, Kp, nullptr, mt, nt, 1024, As, Bs);
  } else {
    gemm_tile<bf16_t, false>(Wv, x, Vt, nullptr, nt, mt, 4096, As, Bs);
  }
}

__global__ __launch_bounds__(256) void out_proj_kernel(
    const bf16_t* __restrict__ Ao, const bf16_t* __restrict__ Wo,
    const float* __restrict__ bias, float* __restrict__ out) {
  __shared__ alignas(16) bf16_t As[128 * 64];
  __shared__ alignas(16) bf16_t Bs[128 * 64];
  const int bid = blockIdx.x;
  gemm_tile<float, true>(Ao, Wo, out, bias, (bid & 31) * 128, (bid >> 5) * 128, 1024, As, Bs);
}

// ---------------------------------------------------------------------------
// Attention R9: R8 design with the scratch-spill bug fixed. The double buffer
// is two explicitly-named register sets (krA/vrA, krB/vrB) consumed in a
// manually 2x-stepped loop -> every register index is compile-time (R8's
// kr[cur] with runtime cur forced the arrays to scratch: 2.7 ms, MfmaUtil 0.8%).
// KV tile 128, 16 barrier-pairs/block; prefetch of tile t+1 issues right
// after tile t's LDS stores and overlaps the 8-step compute phase.
// S^T = K(A,LDS) x Q(B,regs); C-layout (kv=lq*4+r, q=lr) equals the 16x16x16
// B-layout, so P = exp2(S^T) feeds O^T += Vt(A,LDS) x P from registers.
// ---------------------------------------------------------------------------
#define VPAD 132   // V row stride: 66 words ≡ 2 mod 32 -> 2-way on stores, free

#define ATTN_TILE(KR, VR, KRN, VRN, T, DO_PREFETCH)                            \
  {                                                                            \
    __syncthreads();                                                           \
    _Pragma("unroll")                                                          \
    for (int j = 0; j < 4; ++j) st8(&Ks[(size_t)tid * 8 + j * 2048], KR[j]);   \
    st8(&Vs[srow * VPAD + sc0], VR[0]);                                        \
    st8(&Vs[srow * VPAD + sc1], VR[1]);                                        \
    st8(&Vs[(srow + 32) * VPAD + sc0], VR[2]);                                 \
    st8(&Vs[(srow + 32) * VPAD + sc1], VR[3]);                                 \
    __syncthreads();                                                           \
    if (DO_PREFETCH) {                                                         \
      const size_t kv0p = (size_t)((T) + 1) * 128;                             \
      const bf16_t* Kg = Kp + (tok0 + kv0p) * 1024 + col0;                     \
      const bf16_t* Vg = Vt + (size_t)col0 * 4096 + tok0 + kv0p;               \
      _Pragma("unroll")                                                        \
      for (int j = 0; j < 4; ++j)                                              \
        KRN[j] = ldg8(Kg + (size_t)(srow + 32 * j) * 1024 + sxk);              \
      VRN[0] = ldg8(Vg + (size_t)srow * 4096 + sc0);                           \
      VRN[1] = ldg8(Vg + (size_t)srow * 4096 + sc1);                           \
      VRN[2] = ldg8(Vg + (size_t)(srow + 32) * 4096 + sc0);                    \
      VRN[3] = ldg8(Vg + (size_t)(srow + 32) * 4096 + sc1);                    \
    }                                                                          \
    _Pragma("unroll")                                                          \
    for (int c = 0; c < 8; ++c) {                                              \
      const bf16x8 kf0 = ldg8(&Ks[(c * 16 + lr) * 64 + kch0]);                 \
      const bf16x8 kf1 = ldg8(&Ks[(c * 16 + lr) * 64 + kch1]);                 \
      bf16x4 pb[2];                                                            \
      _Pragma("unroll")                                                        \
      for (int nt = 0; nt < 2; ++nt) {                                         \
        f32x4 sT = {0.f, 0.f, 0.f, 0.f};                                       \
        sT = MFMA(kf0, qf[nt][0], sT);                                         \
        sT = MFMA(kf1, qf[nt][1], sT);                                         \
        const float p0 = exp2f(sT.x);                                          \
        const float p1 = exp2f(sT.y);                                          \
        const float p2 = exp2f(sT.z);                                          \
        const float p3 = exp2f(sT.w);                                          \
        pb[nt][0] = (__bf16)p0; pb[nt][1] = (__bf16)p1;                        \
        pb[nt][2] = (__bf16)p2; pb[nt][3] = (__bf16)p3;                        \
        lsum[nt] += (p0 + p1) + (p2 + p3);                                     \
      }                                                                        \
      _Pragma("unroll")                                                        \
      for (int ht = 0; ht < 4; ++ht) {                                         \
        const bf16x4 vf = ldg4(&Vs[(ht * 16 + lr) * VPAD + lq * 4 + c * 16]);  \
        o[0][ht] = mfma16(vf, pb[0], o[0][ht]);                                \
        o[1][ht] = mfma16(vf, pb[1], o[1][ht]);                                \
      }                                                                        \
    }                                                                          \
  }

__global__ __launch_bounds__(256) void attn_kernel(
    const bf16_t* __restrict__ Q, const bf16_t* __restrict__ Kp,
    const bf16_t* __restrict__ Vt, bf16_t* __restrict__ Ao) {
  __shared__ alignas(16) char smem_raw[16384 + 64 * VPAD * 2];  // 33280 B
  bf16_t* Ks  = (bf16_t*)smem_raw;                 // [128 kv][64 hd], swizzled chunks
  bf16_t* Vs  = (bf16_t*)(smem_raw + 16384);       // [64 hd][VPAD kv]
  float*  Osc = (float*)smem_raw;                  // epilogue overlay (17408 B used)

  const int tid  = threadIdx.x;
  const int lane = tid & 63;
  const int wave = tid >> 6;
  const int lr   = lane & 15;
  const int lq   = lane >> 4;
  const int bh   = blockIdx.x;
  const int qt   = blockIdx.y;
  const int b    = bh >> 4;
  const int h    = bh & 15;
  const size_t tok0 = (size_t)b * 2048;
  const int col0 = h * 64;
  const int qblk = qt * 128 + wave * 32;           // wave's 32 q-rows

  // Q B-frags (n = q = lane&15, k = hd = c*32 + lq*8 + i), held in regs
  bf16x8 qf[2][2];
#pragma unroll
  for (int nt = 0; nt < 2; ++nt) {
    const size_t qrow = tok0 + qblk + nt * 16 + lr;
#pragma unroll
    for (int c = 0; c < 2; ++c)
      qf[nt][c] = ldg8(&Q[qrow * 1024 + col0 + c * 32 + lq * 8]);
  }

  f32x4 o[2][4];  // O^T accum per nt: D[m=hd=ht*16+lq*4+r][n=q=lr]
#pragma unroll
  for (int nt = 0; nt < 2; ++nt)
#pragma unroll
    for (int i = 0; i < 4; ++i) o[nt][i] = (f32x4){0.f, 0.f, 0.f, 0.f};
  float lsum[2] = {0.f, 0.f};

  // staging geometry (per thread: 4 K rows, 2 V rows x 2 chunks)
  const int srow = tid >> 3;                       // 0..31
  const int sxk  = ((tid & 7) ^ (srow & 7)) << 3;  // K swizzled source chunk
  const int sc0  = (tid & 7) << 3;                 // V chunk (kv 0..63)
  const int sc1  = sc0 + 64;                       // V chunk (kv 64..127)

  // frag-read LDS offsets
  const int kch0 = (lq ^ (lr & 7)) << 3;
  const int kch1 = ((lq + 4) ^ (lr & 7)) << 3;

  // register double-buffer (explicit names -> compile-time indices only)
  bf16x8 krA[4], vrA[4], krB[4], vrB[4];
  {
    const bf16_t* Kg = Kp + tok0 * 1024 + col0;
    const bf16_t* Vg = Vt + (size_t)col0 * 4096 + tok0;
#pragma unroll
    for (int j = 0; j < 4; ++j) krA[j] = ldg8(Kg + (size_t)(srow + 32 * j) * 1024 + sxk);
    vrA[0] = ldg8(Vg + (size_t)srow * 4096 + sc0);
    vrA[1] = ldg8(Vg + (size_t)srow * 4096 + sc1);
    vrA[2] = ldg8(Vg + (size_t)(srow + 32) * 4096 + sc0);
    vrA[3] = ldg8(Vg + (size_t)(srow + 32) * 4096 + sc1);
  }

  for (int t = 0; t < 16; t += 2) {
    ATTN_TILE(krA, vrA, krB, vrB, t, true);
    ATTN_TILE(krB, vrB, krA, vrA, t + 1, (t + 1) < 15);
  }

  // all waves done with Ks/Vs before overlaying epilogue scratch
  __syncthreads();

  float* Ow = &Osc[wave * 64 * 17];
#pragma unroll
  for (int nt = 0; nt < 2; ++nt) {
    float ls = lsum[nt];
    ls += __shfl_xor(ls, 16);
    ls += __shfl_xor(ls, 32);
    const float invl = 1.f / ls;

    // wave-private transpose bounce (in-wave DS ordering, no barrier)
#pragma unroll
    for (int ht = 0; ht < 4; ++ht)
#pragma unroll
      for (int r = 0; r < 4; ++r)
        Ow[(ht * 16 + lq * 4 + r) * 17 + lr] = o[nt][ht][r] * invl;

    const int qq = lane >> 2;          // 0..15
    const int hc = (lane & 3) * 16;    // hd segment
    bf16x8 w0, w1;
#pragma unroll
    for (int i = 0; i < 8; ++i) {
      w0[i] = (__bf16)Ow[(hc + i) * 17 + qq];
      w1[i] = (__bf16)Ow[(hc + 8 + i) * 17 + qq];
    }
    bf16_t* dst = Ao + (tok0 + qblk + nt * 16 + qq) * 1024 + col0 + hc;
    st8(dst, w0);
    st8(dst + 8, w1);
  }
}

extern "C" void kernel_launch(void* const* d_in, const int* in_sizes, int n_in,
                              void* d_out, int out_size, void* d_ws, size_t ws_size,
                              hipStream_t stream) {
  const float* x  = (const float*)d_in[0];
  const float* Wq = (const float*)d_in[1];
  const float* Wk = (const float*)d_in[2];
  const float* Wv = (const float*)d_in[3];
  const float* Wo = (const float*)d_in[4];
  const float* bo = (const float*)d_in[5];
  float* out = (float*)d_out;

  const size_t NTOK = 4096, DMODEL = 1024, WSZ = DMODEL * DMODEL;
  bf16_t* xb  = (bf16_t*)d_ws;
  bf16_t* Wqb = xb + NTOK * DMODEL;
  bf16_t* Wkb = Wqb + WSZ;
  bf16_t* Wvb = Wkb + WSZ;
  bf16_t* Wob = Wvb + WSZ;
  bf16_t* Q   = Wob + WSZ;
  bf16_t* Kp  = Q  + NTOK * DMODEL;
  bf16_t* Vt  = Kp + NTOK * DMODEL;            // [1024][4096] = V^T
  bf16_t* Ao  = Vt + NTOK * DMODEL;

  cvt_kernel<<<dim3(4096), 256, 0, stream>>>(x, Wq, Wk, Wv, Wo, xb, Wqb, Wkb, Wvb, Wob);
  qkv_kernel<<<dim3(256, 3), 256, 0, stream>>>(xb, Wqb, Wkb, Wvb, Q, Kp, Vt);
  attn_kernel<<<dim3(32, 16), 256, 0, stream>>>(Q, Kp, Vt, Ao);
  out_proj_kernel<<<dim3(256, 1), 256, 0, stream>>>(Ao, Wob, bo, out);
}

// Round 10
// 215.546 us; speedup vs baseline: 12.9227x; 1.0334x over previous
//
#include <hip/hip_runtime.h>
#include <hip/hip_bf16.h>

typedef __hip_bfloat16 bf16_t;
typedef __bf16 bf16x8 __attribute__((ext_vector_type(8)));      // 16x16x32 A/B frag
typedef __bf16 bf16x4 __attribute__((ext_vector_type(4)));      // 16x16x16 A/B frag
typedef short  s16x4  __attribute__((ext_vector_type(4)));
typedef float  f32x4  __attribute__((ext_vector_type(4)));      // C/D frag

#define MFMA(a, b, c) __builtin_amdgcn_mfma_f32_16x16x32_bf16((a), (b), (c), 0, 0, 0)

__device__ __forceinline__ f32x4 mfma16(bf16x4 a, bf16x4 b, f32x4 c) {
#if __has_builtin(__builtin_amdgcn_mfma_f32_16x16x16_bf16)
  return __builtin_amdgcn_mfma_f32_16x16x16_bf16(a, b, c, 0, 0, 0);
#else
  return __builtin_amdgcn_mfma_f32_16x16x16bf16_1k(
      __builtin_bit_cast(s16x4, a), __builtin_bit_cast(s16x4, b), c, 0, 0, 0);
#endif
}

__device__ __forceinline__ bf16x8 ldg8(const bf16_t* p) {
  return *reinterpret_cast<const bf16x8*>(p);
}
__device__ __forceinline__ bf16x4 ldg4(const bf16_t* p) {
  return *reinterpret_cast<const bf16x4*>(p);
}
__device__ __forceinline__ void st8(bf16_t* p, bf16x8 v) {
  *reinterpret_cast<bf16x8*>(p) = v;
}
__device__ __forceinline__ void store_out(bf16_t* p, float v) { *p = __float2bfloat16(v); }
__device__ __forceinline__ void store_out(float* p, float v)  { *p = v; }

// async global->LDS, 16B per lane. LDS dest is wave-uniform base + lane*16.
__device__ __forceinline__ void async16(const bf16_t* g, bf16_t* l) {
  __builtin_amdgcn_global_load_lds(
      (const __attribute__((address_space(1))) void*)g,
      (__attribute__((address_space(3))) void*)l, 16, 0, 0);
}

// ---------------------------------------------------------------------------
// f32 -> bf16 conversion; folds softmax scale (1/8 * log2e) into Wq.
// ---------------------------------------------------------------------------
__global__ __launch_bounds__(256) void cvt_kernel(
    const float* __restrict__ x,  const float* __restrict__ Wq,
    const float* __restrict__ Wk, const float* __restrict__ Wv,
    const float* __restrict__ Wo,
    bf16_t* __restrict__ xb,  bf16_t* __restrict__ Wqb,
    bf16_t* __restrict__ Wkb, bf16_t* __restrict__ Wvb,
    bf16_t* __restrict__ Wob) {
  const int bid = blockIdx.x;
  const float* src; bf16_t* dst; size_t base;
  float scl = 1.0f;
  if (bid < 2048)      { src = x;  dst = xb;  base = (size_t)bid * 2048; }
  else if (bid < 2560) { src = Wq; dst = Wqb; base = (size_t)(bid - 2048) * 2048;
                         scl = 0.180336878f; }  // 0.125 * log2(e)
  else if (bid < 3072) { src = Wk; dst = Wkb; base = (size_t)(bid - 2560) * 2048; }
  else if (bid < 3584) { src = Wv; dst = Wvb; base = (size_t)(bid - 3072) * 2048; }
  else                 { src = Wo; dst = Wob; base = (size_t)(bid - 3584) * 2048; }
  const size_t i0 = base + (size_t)threadIdx.x * 8;
  const float4 f0 = *reinterpret_cast<const float4*>(src + i0);
  const float4 f1 = *reinterpret_cast<const float4*>(src + i0 + 4);
  bf16x8 v;
  v[0] = (__bf16)(f0.x * scl); v[1] = (__bf16)(f0.y * scl);
  v[2] = (__bf16)(f0.z * scl); v[3] = (__bf16)(f0.w * scl);
  v[4] = (__bf16)(f1.x * scl); v[5] = (__bf16)(f1.y * scl);
  v[6] = (__bf16)(f1.z * scl); v[7] = (__bf16)(f1.w * scl);
  st8(dst + i0, v);
}

// ---------------------------------------------------------------------------
// GEMM tile: C[128x128] = A[128xK] * B[128xK]^T, K=1024, BK=64.
// global_load_lds width-16 staging with XOR-chunk swizzle.  (unchanged, R6)
// ---------------------------------------------------------------------------
#define GK 1024

template <typename OutT, bool BIAS>
__device__ __forceinline__ void gemm_tile(
    const bf16_t* __restrict__ A, const bf16_t* __restrict__ B,
    OutT* __restrict__ C, const float* __restrict__ bias,
    int bm, int bn, int ldc, bf16_t* As, bf16_t* Bs) {
  const int tid  = threadIdx.x;
  const int lane = tid & 63;
  const int wave = tid >> 6;
  const int wm   = (wave & 1) << 6;
  const int wn   = (wave >> 1) << 6;
  const int lr   = lane & 15;
  const int lq   = lane >> 4;

  const int srow = tid >> 3;                        // 0..31
  const int sx   = ((tid & 7) ^ (srow & 7)) << 3;   // swizzled source offset

  const bf16_t* Ag = A + (size_t)(bm + srow) * GK + sx;
  const bf16_t* Bg = B + (size_t)(bn + srow) * GK + sx;
  bf16_t* Asw = As + wave * 512;
  bf16_t* Bsw = Bs + wave * 512;

  f32x4 acc[4][4];
#pragma unroll
  for (int i = 0; i < 4; ++i)
#pragma unroll
    for (int j = 0; j < 4; ++j) acc[i][j] = (f32x4){0.f, 0.f, 0.f, 0.f};

  for (int k0 = 0; k0 < GK; k0 += 64) {
    __syncthreads();
#pragma unroll
    for (int g = 0; g < 4; ++g) {
      async16(Ag + k0 + (size_t)(g * 32) * GK, Asw + g * 2048);
      async16(Bg + k0 + (size_t)(g * 32) * GK, Bsw + g * 2048);
    }
    __syncthreads();
#pragma unroll
    for (int ks = 0; ks < 2; ++ks) {
      bf16x8 af[4], bf[4];
      const int chs = ((ks * 4 + lq) ^ (lr & 7)) << 3;
#pragma unroll
      for (int i = 0; i < 4; ++i) {
        af[i] = ldg8(&As[(wm + i * 16 + lr) * 64 + chs]);
        bf[i] = ldg8(&Bs[(wn + i * 16 + lr) * 64 + chs]);
      }
#pragma unroll
      for (int mi = 0; mi < 4; ++mi)
#pragma unroll
        for (int ni = 0; ni < 4; ++ni)
          acc[mi][ni] = MFMA(af[mi], bf[ni], acc[mi][ni]);
    }
  }

  // C/D layout: col = lane&15, row = (lane>>4)*4 + r  (m89-verified)
#pragma unroll
  for (int ni = 0; ni < 4; ++ni) {
    const int col = bn + wn + ni * 16 + lr;
    float bv = 0.f;
    if (BIAS) bv = bias[col];
#pragma unroll
    for (int mi = 0; mi < 4; ++mi) {
#pragma unroll
      for (int r = 0; r < 4; ++r) {
        const int row = bm + wm + mi * 16 + lq * 4 + r;
        store_out(&C[(size_t)row * ldc + col], acc[mi][ni][r] + bv);
      }
    }
  }
}

// XCD-aware remap: same-x-tile blocks share bid%8 -> same XCD L2.
// z=0: Q = x Wq^T;  z=1: K = x Wk^T;  z=2: Vt = Wv x^T [1024x4096]
__global__ __launch_bounds__(256) void qkv_kernel(
    const bf16_t* __restrict__ x, const bf16_t* __restrict__ Wq,
    const bf16_t* __restrict__ Wk, const bf16_t* __restrict__ Wv,
    bf16_t* __restrict__ Q, bf16_t* __restrict__ Kp, bf16_t* __restrict__ Vt) {
  __shared__ alignas(16) bf16_t As[128 * 64];
  __shared__ alignas(16) bf16_t Bs[128 * 64];
  const int bid = blockIdx.x;
  const int z   = blockIdx.y;
  const int mt  = (bid & 31) * 128;   // x token-tile; XCD = bid%8 = mt-tile%8
  const int nt  = (bid >> 5) * 128;
  if (z == 0) {
    gemm_tile<bf16_t, false>(x, Wq, Q, nullptr, mt, nt, 1024, As, Bs);
  } else if (z == 1) {
    gemm_tile<bf16_t, false>(x, Wk, Kp, nullptr, mt, nt, 1024, As, Bs);
  } else {
    gemm_tile<bf16_t, false>(Wv, x, Vt, nullptr, nt, mt, 4096, As, Bs);
  }
}

__global__ __launch_bounds__(256) void out_proj_kernel(
    const bf16_t* __restrict__ Ao, const bf16_t* __restrict__ Wo,
    const float* __restrict__ bias, float* __restrict__ out) {
  __shared__ alignas(16) bf16_t As[128 * 64];
  __shared__ alignas(16) bf16_t Bs[128 * 64];
  const int bid = blockIdx.x;
  gemm_tile<float, true>(Ao, Wo, out, bias, (bid & 31) * 128, (bid >> 5) * 128, 1024, As, Bs);
}

// ---------------------------------------------------------------------------
// Attention R10: R6 compute core (32 q/wave, S^T register-P, KV=64) +
// LDS DOUBLE-BUFFER with ONE barrier per tile. 2-wave blocks (64 q), grid
// (32 bh, 32 qt) = 1024 blocks -> 4 independent blocks/CU (33.8 KB LDS).
// Per tile: barrier -> issue async-K(nxt) + V-ldg(regs) -> compute cur ->
// st8 V->nxt. Staging latency resolves during compute; the barrier's vmcnt
// drain finds loads already landed (m97 trick applied to attention).
// Buffers are macro-named (no dynamic register indexing - R8 lesson).
// ---------------------------------------------------------------------------
#define VPAD 68

#define ATTN_TILE(KC, VC, KN, VN, VRN, T)                                      \
  {                                                                            \
    __syncthreads();                                                           \
    if ((T) < 31) {                                                            \
      const size_t kv0p = (size_t)((T) + 1) * 64;                              \
      const bf16_t* Kg = Kp + (tok0 + kv0p) * 1024 + col0;                     \
      const bf16_t* Vg = Vt + (size_t)col0 * 4096 + tok0 + kv0p;               \
      _Pragma("unroll")                                                        \
      for (int r = 0; r < 4; ++r)                                              \
        async16(Kg + (size_t)(r * 16 + trow) * 1024 + sxk,                     \
                KN + r * 1024 + wave * 512);                                   \
      _Pragma("unroll")                                                        \
      for (int r = 0; r < 4; ++r)                                              \
        VRN[r] = ldg8(Vg + (size_t)(r * 16 + trow) * 4096 + tcol);             \
    }                                                                          \
    _Pragma("unroll")                                                          \
    for (int c = 0; c < 4; ++c) {                                              \
      const bf16x8 kf0 = ldg8(&KC[(c * 16 + lr) * 64 + kch0]);                 \
      const bf16x8 kf1 = ldg8(&KC[(c * 16 + lr) * 64 + kch1]);                 \
      bf16x4 pb[2];                                                            \
      _Pragma("unroll")                                                        \
      for (int nt = 0; nt < 2; ++nt) {                                         \
        f32x4 sT = {0.f, 0.f, 0.f, 0.f};                                       \
        sT = MFMA(kf0, qf[nt][0], sT);                                         \
        sT = MFMA(kf1, qf[nt][1], sT);                                         \
        const float p0 = exp2f(sT.x);                                          \
        const float p1 = exp2f(sT.y);                                          \
        const float p2 = exp2f(sT.z);                                          \
        const float p3 = exp2f(sT.w);                                          \
        pb[nt][0] = (__bf16)p0; pb[nt][1] = (__bf16)p1;                        \
        pb[nt][2] = (__bf16)p2; pb[nt][3] = (__bf16)p3;                        \
        lsum[nt] += (p0 + p1) + (p2 + p3);                                     \
      }                                                                        \
      _Pragma("unroll")                                                        \
      for (int ht = 0; ht < 4; ++ht) {                                         \
        const bf16x4 vf = ldg4(&VC[(ht * 16 + lr) * VPAD + lq * 4 + c * 16]);  \
        o[0][ht] = mfma16(vf, pb[0], o[0][ht]);                                \
        o[1][ht] = mfma16(vf, pb[1], o[1][ht]);                                \
      }                                                                        \
    }                                                                          \
    if ((T) < 31) {                                                            \
      _Pragma("unroll")                                                        \
      for (int r = 0; r < 4; ++r)                                              \
        st8(&VN[(r * 16 + trow) * VPAD + tcol], VRN[r]);                       \
    }                                                                          \
  }

__global__ __launch_bounds__(128) void attn_kernel(
    const bf16_t* __restrict__ Q, const bf16_t* __restrict__ Kp,
    const bf16_t* __restrict__ Vt, bf16_t* __restrict__ Ao) {
  __shared__ alignas(16) char smem_raw[16384 + 2 * 64 * VPAD * 2];  // 33792 B
  bf16_t* KsA = (bf16_t*)smem_raw;                   // [64 kv][64 hd] swizzled
  bf16_t* KsB = (bf16_t*)(smem_raw + 8192);
  bf16_t* VsA = (bf16_t*)(smem_raw + 16384);         // [64 hd][VPAD kv]
  bf16_t* VsB = (bf16_t*)(smem_raw + 16384 + 64 * VPAD * 2);
  float*  Osc = (float*)smem_raw;                    // epilogue overlay (8.7 KB)

  const int tid  = threadIdx.x;                      // 0..127 (2 waves)
  const int lane = tid & 63;
  const int wave = tid >> 6;
  const int lr   = lane & 15;
  const int lq   = lane >> 4;
  const int bh   = blockIdx.x;
  const int qt   = blockIdx.y;
  const int b    = bh >> 4;
  const int h    = bh & 15;
  const size_t tok0 = (size_t)b * 2048;
  const int col0 = h * 64;
  const int qblk = qt * 64 + wave * 32;              // wave's 32 q-rows

  // Q B-frags (n = q = lane&15, k = hd = c*32 + lq*8 + i), held in regs
  bf16x8 qf[2][2];
#pragma unroll
  for (int nt = 0; nt < 2; ++nt) {
    const size_t qrow = tok0 + qblk + nt * 16 + lr;
#pragma unroll
    for (int c = 0; c < 2; ++c)
      qf[nt][c] = ldg8(&Q[qrow * 1024 + col0 + c * 32 + lq * 8]);
  }

  f32x4 o[2][4];  // O^T accum per nt: D[m=hd=ht*16+lq*4+r][n=q=lr]
#pragma unroll
  for (int nt = 0; nt < 2; ++nt)
#pragma unroll
    for (int i = 0; i < 4; ++i) o[nt][i] = (f32x4){0.f, 0.f, 0.f, 0.f};
  float lsum[2] = {0.f, 0.f};

  // staging geometry: 128 threads, 4 rounds of 16 rows x 8 chunks
  const int trow = tid >> 3;                        // 0..15
  const int sxk  = ((tid & 7) ^ (trow & 7)) << 3;   // K swizzled source chunk
  const int tcol = (tid & 7) << 3;                  // V chunk

  // frag-read LDS chunk offsets (XOR-swizzled K)
  const int kch0 = (lq ^ (lr & 7)) << 3;
  const int kch1 = ((lq + 4) ^ (lr & 7)) << 3;

  bf16x8 vrA[4], vrB[4];

  // prologue: stage tile 0 into A
  {
    const bf16_t* Kg = Kp + tok0 * 1024 + col0;
    const bf16_t* Vg = Vt + (size_t)col0 * 4096 + tok0;
#pragma unroll
    for (int r = 0; r < 4; ++r)
      async16(Kg + (size_t)(r * 16 + trow) * 1024 + sxk, KsA + r * 1024 + wave * 512);
#pragma unroll
    for (int r = 0; r < 4; ++r)
      vrA[r] = ldg8(Vg + (size_t)(r * 16 + trow) * 4096 + tcol);
#pragma unroll
    for (int r = 0; r < 4; ++r)
      st8(&VsA[(r * 16 + trow) * VPAD + tcol], vrA[r]);
  }

  for (int t = 0; t < 32; t += 2) {
    ATTN_TILE(KsA, VsA, KsB, VsB, vrB, t);
    ATTN_TILE(KsB, VsB, KsA, VsA, vrA, t + 1);
  }

  // all waves done with K/V buffers before overlaying epilogue scratch
  __syncthreads();

  float* Ow = &Osc[wave * 64 * 17];
#pragma unroll
  for (int nt = 0; nt < 2; ++nt) {
    float ls = lsum[nt];
    ls += __shfl_xor(ls, 16);
    ls += __shfl_xor(ls, 32);
    const float invl = 1.f / ls;

    // wave-private transpose bounce (in-wave DS ordering, no barrier)
#pragma unroll
    for (int ht = 0; ht < 4; ++ht)
#pragma unroll
      for (int r = 0; r < 4; ++r)
        Ow[(ht * 16 + lq * 4 + r) * 17 + lr] = o[nt][ht][r] * invl;

    const int qq = lane >> 2;          // 0..15
    const int hc = (lane & 3) * 16;    // hd segment
    bf16x8 w0, w1;
#pragma unroll
    for (int i = 0; i < 8; ++i) {
      w0[i] = (__bf16)Ow[(hc + i) * 17 + qq];
      w1[i] = (__bf16)Ow[(hc + 8 + i) * 17 + qq];
    }
    bf16_t* dst = Ao + (tok0 + qblk + nt * 16 + qq) * 1024 + col0 + hc;
    st8(dst, w0);
    st8(dst + 8, w1);
  }
}

extern "C" void kernel_launch(void* const* d_in, const int* in_sizes, int n_in,
                              void* d_out, int out_size, void* d_ws, size_t ws_size,
                              hipStream_t stream) {
  const float* x  = (const float*)d_in[0];
  const float* Wq = (const float*)d_in[1];
  const float* Wk = (const float*)d_in[2];
  const float* Wv = (const float*)d_in[3];
  const float* Wo = (const float*)d_in[4];
  const float* bo = (const float*)d_in[5];
  float* out = (float*)d_out;

  const size_t NTOK = 4096, DMODEL = 1024, WSZ = DMODEL * DMODEL;
  bf16_t* xb  = (bf16_t*)d_ws;
  bf16_t* Wqb = xb + NTOK * DMODEL;
  bf16_t* Wkb = Wqb + WSZ;
  bf16_t* Wvb = Wkb + WSZ;
  bf16_t* Wob = Wvb + WSZ;
  bf16_t* Q   = Wob + WSZ;
  bf16_t* Kp  = Q  + NTOK * DMODEL;
  bf16_t* Vt  = Kp + NTOK * DMODEL;            // [1024][4096] = V^T
  bf16_t* Ao  = Vt + NTOK * DMODEL;

  cvt_kernel<<<dim3(4096), 256, 0, stream>>>(x, Wq, Wk, Wv, Wo, xb, Wqb, Wkb, Wvb, Wob);
  qkv_kernel<<<dim3(256, 3), 256, 0, stream>>>(xb, Wqb, Wkb, Wvb, Q, Kp, Vt);
  attn_kernel<<<dim3(32, 32), 128, 0, stream>>>(Q, Kp, Vt, Ao);
  out_proj_kernel<<<dim3(256, 1), 256, 0, stream>>>(Ao, Wob, bo, out);
}